// Round 8
// baseline (5430.411 us; speedup 1.0000x reference)
//
#include <hip/hip_runtime.h>
#include <stdint.h>

// ---------------- problem constants ----------------
#define T_STEPS 1000
#define B_SZ    32
#define NI      512
#define NH      1024
#define NO      256

// R14: sequential two-batch interleave.  Block (g, sl) owns neurons
// j in [128sl, 128sl+128) of batches bX = g and bY = g+16.  128 blocks x 256
// threads (co-residency trivially safe).  Program order per step:
//   stateX+pubX, stateY+pubY | pollX+compactX || (nothing)
//   gatherX (w0,w1: A-dword; w3: B-float2)    || pollY+compactY (w2)
//   pscX, gatherY                              (Y's RT fully hidden)
//   pscY
// The MALL round trip for Y costs nothing; only part of X's RT is exposed
// per PAIR of batch-steps.  R10/R12 tried this with concurrent blocks and
// failed (in-phase lock, doubled spin traffic); sequential interleave forces
// the anti-phase by construction.
#define NSLICE  8
#define NGRP    16
#define NBLK    (NGRP * NSLICE)   // 128 scan blocks

// WTS slices get 16 pad rows; row NH (=1024) of each slice is ZERO and is
// the dummy gather target used to pad spike lists to multiples of 16.
#define NHP     (NH + 16)
#define DUMMY   NH
#define BOFF    544               // slist offset of the B-half region

#define D1C 0.90483741803595957f  // exp(-0.1)
#define D2C 0.81873075307798186f  // exp(-0.2) == decay_syn

typedef unsigned long long u64;

// ---------------- ws layout (bytes) ----------------
#define OFF_IEXT 0ull
#define SZ_IEXT  ((unsigned long long)T_STEPS * B_SZ * NH * 4ull)   // 131,072,000
#define OFF_WTS  (OFF_IEXT + SZ_IEXT)
#define SZ_WTS   ((unsigned long long)NSLICE * NHP * 128 * 4ull)    // 4.06 MiB
#define OFF_RATE (OFF_WTS + SZ_WTS)
#define SZ_RATE  ((unsigned long long)B_SZ * NH * 4ull)             // 128 KiB
#define OFF_SYNC (OFF_RATE + SZ_RATE)
#define SZ_SYNC  ((unsigned long long)2 * B_SZ * NSLICE * 4 * 8ull) // 16 KiB

// ---------------- agent-scope helpers ----------------
__device__ __forceinline__ u64 ld64_agent(const u64* p) {
  return __hip_atomic_load(p, __ATOMIC_RELAXED, __HIP_MEMORY_SCOPE_AGENT);
}
__device__ __forceinline__ void st64_agent(u64* p, u64 v) {
  __hip_atomic_store(p, v, __ATOMIC_RELAXED, __HIP_MEMORY_SCOPE_AGENT);
}

// ---------------- kernel 1: transpose W_rec -> WTS (unchanged) ----------------
__global__ __launch_bounds__(256) void prep_wts(const float* __restrict__ Wrec,
                                                float* __restrict__ WTS) {
  __shared__ float tile[64][65];
  const int tid = threadIdx.x;
  const int j0 = blockIdx.x * 64;
  const int i0 = blockIdx.y * 64;
  const int sl = j0 >> 7;
  const int jjb = j0 & 127;
#pragma unroll
  for (int k = 0; k < 16; ++k) {
    const int idx = k * 256 + tid;
    const int jl = idx >> 6, il = idx & 63;
    tile[jl][il] = Wrec[(size_t)(j0 + jl) * NH + i0 + il];
  }
  __syncthreads();
#pragma unroll
  for (int k = 0; k < 16; ++k) {
    const int idx = k * 256 + tid;
    const int il = idx >> 6, jl = idx & 63;
    WTS[((size_t)(sl * NHP + i0 + il)) * 128 + jjb + jl] = tile[jl][il];
  }
}

// ---------------- kernel 2: I_ext = x @ W_in^T  (fp32 tiled, unchanged) ----------------
#define GBM 128
#define GBN 128
#define GBK 16
__global__ __launch_bounds__(256) void gemm_in(const float* __restrict__ X,
                                               const float* __restrict__ Win,
                                               float* __restrict__ I) {
  __shared__ float As[GBK][GBM + 4];
  __shared__ float Bs[GBK][GBN + 4];
  const int tid = threadIdx.x;
  const int m0 = blockIdx.x * GBM;
  const int n0 = blockIdx.y * GBN;
  const int tm = tid >> 4, tn = tid & 15;
  const int lr = tid >> 1, lk = (tid & 1) * 8;
  float acc[8][8] = {};
  for (int k0 = 0; k0 < NI; k0 += GBK) {
    float4 a0 = *(const float4*)&X[(size_t)(m0 + lr) * NI + k0 + lk];
    float4 a1 = *(const float4*)&X[(size_t)(m0 + lr) * NI + k0 + lk + 4];
    float4 b0 = *(const float4*)&Win[(size_t)(n0 + lr) * NI + k0 + lk];
    float4 b1 = *(const float4*)&Win[(size_t)(n0 + lr) * NI + k0 + lk + 4];
    As[lk + 0][lr] = a0.x; As[lk + 1][lr] = a0.y; As[lk + 2][lr] = a0.z; As[lk + 3][lr] = a0.w;
    As[lk + 4][lr] = a1.x; As[lk + 5][lr] = a1.y; As[lk + 6][lr] = a1.z; As[lk + 7][lr] = a1.w;
    Bs[lk + 0][lr] = b0.x; Bs[lk + 1][lr] = b0.y; Bs[lk + 2][lr] = b0.z; Bs[lk + 3][lr] = b0.w;
    Bs[lk + 4][lr] = b1.x; Bs[lk + 5][lr] = b1.y; Bs[lk + 6][lr] = b1.z; Bs[lk + 7][lr] = b1.w;
    __syncthreads();
#pragma unroll
    for (int k = 0; k < GBK; ++k) {
      float av[8], bv[8];
      *(float4*)&av[0] = *(const float4*)&As[k][tm * 8];
      *(float4*)&av[4] = *(const float4*)&As[k][tm * 8 + 4];
      *(float4*)&bv[0] = *(const float4*)&Bs[k][tn * 8];
      *(float4*)&bv[4] = *(const float4*)&Bs[k][tn * 8 + 4];
#pragma unroll
      for (int i2 = 0; i2 < 8; ++i2)
#pragma unroll
        for (int j2 = 0; j2 < 8; ++j2) acc[i2][j2] += av[i2] * bv[j2];
    }
    __syncthreads();
  }
#pragma unroll
  for (int i2 = 0; i2 < 8; ++i2) {
    float4 c0 = {acc[i2][0], acc[i2][1], acc[i2][2], acc[i2][3]};
    float4 c1 = {acc[i2][4], acc[i2][5], acc[i2][6], acc[i2][7]};
    *(float4*)&I[(size_t)(m0 + tm * 8 + i2) * NH + n0 + tn * 8] = c0;
    *(float4*)&I[(size_t)(m0 + tm * 8 + i2) * NH + n0 + tn * 8 + 4] = c1;
  }
}

// ---------------- scan helpers (verbatim R9 logic, parameterized) ----------------

// state update + publish for one batch (op order matches reference exactly)
__device__ __forceinline__ void state_pub(float& v, float& A1, float& A2, float& rf,
                                          const float psc, const float ip, int& sc,
                                          u64* gb, const int sl, const int wv,
                                          const int ln, const int t) {
  const float I = ip + psc;
  A1 *= D1C; A2 *= D2C;
  v = v + ((-60.0f - v) / 20.0f + (I + A1 + A2) / 2.0f);
  const bool inref = rf > 0.0f;
  if (inref) v = -60.0f;
  const bool spike = (!inref) && (v >= -45.0f);
  if (spike) { v = -60.0f; A1 += 1.0f; A2 += -2.0f; rf = 2.0f; sc++; }
  else       { rf = fmaxf(rf - 1.0f, 0.0f); }
  const u64 bal = __ballot(spike);   // bit ln = spike(j = 128*sl + 64*wv + ln)
  if (ln < 2) {
    const int w = wv * 2 + ln;       // word w covers neurons 128*sl + 32w ..
    const unsigned payload = ln ? (unsigned)(bal >> 32) : (unsigned)bal;
    st64_agent(&gb[sl * 4 + w], (u64)payload | ((u64)(unsigned)(t + 1) << 32));
  }
}

// poll one batch's 32 words + compact -> padded split lists (verbatim R9 wave-2)
__device__ __forceinline__ void poll_compact(u64* gbase, const unsigned want,
                                             const int ln,
                                             unsigned short* sl_, int* sc_) {
  u64 val = 0;
  const u64* gp = &gbase[ln & 31];
  for (;;) {
    if (ln < 32) val = ld64_agent(gp);
    const bool ok = (ln >= 32) || ((unsigned)(val >> 32) == want);
    if (__all(ok)) break;
  }
  unsigned myw = (ln < 32) ? (unsigned)val : 0u;
  int inc = __popc(myw);
#pragma unroll
  for (int d = 1; d < 32; d <<= 1) {
    int y = __shfl_up(inc, d);
    if (ln >= d) inc += y;
  }
  const int cntA = __shfl(inc, 15);
  const int cnt  = __shfl(inc, 31);
  if (ln < 32) {
    int off = inc - __popc(myw);        // global exclusive offset
    if (ln >= 16) off += BOFF - cntA;   // B entries go to their own region
    const int base = ln * 32;
    unsigned m = myw;
    while (m) {
      const int bit = __builtin_ctz(m);
      m &= m - 1;
      sl_[off++] = (unsigned short)(base + bit);
    }
  }
  // pad each half to multiple of 16 plus one extra dummy batch; DUMMY row is
  // zero -> each pad add is s += +0.0f, a bit-exact identity.
  const int cB   = cnt - cntA;
  const int cA16 = ((cntA + 15) & ~15) + 16;   // <= 544
  const int cB16 = ((cB   + 15) & ~15) + 16;   // <= 544
  if (ln < cA16 - cntA) sl_[cntA + ln]      = (unsigned short)DUMMY;
  if (ln < cB16 - cB)   sl_[BOFF + cB + ln] = (unsigned short)DUMMY;
  if (ln == 0) { sc_[0] = cA16; sc_[1] = cB16; }
}

// A-half gather: 1 j per thread, dword loads, tail-free 16-deep (verbatim R9)
__device__ __forceinline__ float gather_A(const float* wts, const unsigned short* sl_,
                                          const int kEnd, const int jloc) {
  float s = 0.0f;
  float wv16[16];
#pragma unroll
  for (int m2 = 0; m2 < 16; ++m2)
    wv16[m2] = wts[(size_t)sl_[m2] * 128 + jloc];
  for (int k = 16; k < kEnd; k += 16) {
    float nv16[16];
#pragma unroll
    for (int m2 = 0; m2 < 16; ++m2)
      nv16[m2] = wts[(size_t)sl_[k + m2] * 128 + jloc];
#pragma unroll
    for (int m2 = 0; m2 < 16; ++m2) s += wv16[m2];   // in-order adds
#pragma unroll
    for (int m2 = 0; m2 < 16; ++m2) wv16[m2] = nv16[m2];
  }
#pragma unroll
  for (int m2 = 0; m2 < 16; ++m2) s += wv16[m2];
  return s;
}

// B-half gather: one wave, 2 consecutive j per lane via float2.  Componentwise
// adds in list order -> per-j fold bit-identical to the scalar chain.
__device__ __forceinline__ void gather_B2(const float* wts, const unsigned short* sl_,
                                          const int kEnd, const int ln, float* ps) {
  float sx = 0.0f, sy = 0.0f;
  const unsigned short* lb = sl_ + BOFF;
  float2 wv16[16];
#pragma unroll
  for (int m2 = 0; m2 < 16; ++m2)
    wv16[m2] = *(const float2*)&wts[(size_t)lb[m2] * 128 + 2 * ln];
  for (int k = 16; k < kEnd; k += 16) {
    float2 nv16[16];
#pragma unroll
    for (int m2 = 0; m2 < 16; ++m2)
      nv16[m2] = *(const float2*)&wts[(size_t)lb[k + m2] * 128 + 2 * ln];
#pragma unroll
    for (int m2 = 0; m2 < 16; ++m2) { sx += wv16[m2].x; sy += wv16[m2].y; }
#pragma unroll
    for (int m2 = 0; m2 < 16; ++m2) wv16[m2] = nv16[m2];
  }
#pragma unroll
  for (int m2 = 0; m2 < 16; ++m2) { sx += wv16[m2].x; sy += wv16[m2].y; }
  ps[2 * ln]     = sx;
  ps[2 * ln + 1] = sy;
}

// ---------------- kernel 3: persistent 1000-step scan, two batches per block ----------------
__global__ __launch_bounds__(256) void scan_rsnn(const float* __restrict__ Iext,
                                                 const float* __restrict__ WTS,
                                                 float* __restrict__ rate,
                                                 u64* sync) {
  __shared__ unsigned short slist[2][1088];  // [0]=batch X, [1]=batch Y
  __shared__ int   scnt[2][2];               // padded counts per batch
  __shared__ float psum[2][128];             // B-half partial sums per batch

  const int bid = blockIdx.x;
  const int g   = bid >> 3;                  // group 0..15
  const int sl  = bid & 7;                   // slice == bid%8 == XCD (perf heuristic)
  const int bX  = g;
  const int bY  = g + 16;
  const int tid = threadIdx.x;
  const int wv  = tid >> 6;
  const int ln  = tid & 63;

  const float* wts = WTS + (size_t)sl * NHP * 128;

  // per-neuron state for BOTH batches (waves 0-1; neuron j = 128*sl + tid)
  float vX = -60.0f, A1X = 0.0f, A2X = 0.0f, rfX = 0.0f, hX = 0.0f, pscX = 0.0f, ipX = 0.0f;
  float vY = -60.0f, A1Y = 0.0f, A2Y = 0.0f, rfY = 0.0f, hY = 0.0f, pscY = 0.0f, ipY = 0.0f;
  int scX = 0, scY = 0;

  if (tid < 128) {
    ipX = Iext[(size_t)bX * NH + sl * 128 + tid];
    ipY = Iext[(size_t)bY * NH + sl * 128 + tid];
  }

  for (int t = 0; t < T_STEPS; ++t) {
    const int par = t & 1;
    const unsigned want = (unsigned)(t + 1);
    u64* gX = sync + ((size_t)(par * B_SZ + bX)) * (NSLICE * 4);
    u64* gY = sync + ((size_t)(par * B_SZ + bY)) * (NSLICE * 4);

    // ---- phase 1: state+publish X then Y (w0-1) || pollX+compactX (w2) ----
    if (tid < 128) {
      state_pub(vX, A1X, A2X, rfX, pscX, ipX, scX, gX, sl, wv, ln, t);
      state_pub(vY, A1Y, A2Y, rfY, pscY, ipY, scY, gY, sl, wv, ln, t);
      __builtin_amdgcn_sched_barrier(0);    // keep prefetches below the publishes
      const int tn2 = (t + 1 < T_STEPS) ? t + 1 : t;
      ipX = Iext[((size_t)tn2 * B_SZ + bX) * NH + sl * 128 + tid];
      ipY = Iext[((size_t)tn2 * B_SZ + bY) * NH + sl * 128 + tid];
    } else if (wv == 2) {
      poll_compact(gX, want, ln, slist[0], scnt[0]);
    }
    __syncthreads();   // alpha: slistX/scntX ready

    // ---- phase 2: gatherX (w0,w1 A-half; w3 B-half) || pollY+compactY (w2) ----
    float sAX = 0.0f;
    if (tid < 128)       sAX = gather_A(wts, slist[0], scnt[0][0], tid);
    else if (wv == 3)    gather_B2(wts, slist[0], scnt[0][1], ln, psum[0]);
    else /* wv == 2 */   poll_compact(gY, want, ln, slist[1], scnt[1]);
    __syncthreads();   // beta: psumX ready + slistY/scntY ready

    // ---- phase 3: pscX update + gatherY ----
    float sAY = 0.0f;
    if (tid < 128) {
      const float recX = sAX + psum[0][tid];   // A+B, same association as R9
      hX = D2C * hX + recX;
      pscX = D2C * pscX + hX;                  // psc uses updated h (matches reference)
      sAY = gather_A(wts, slist[1], scnt[1][0], tid);
    } else if (wv == 3) {
      gather_B2(wts, slist[1], scnt[1][1], ln, psum[1]);
    }
    __syncthreads();   // gamma: psumY ready; also guards slist overwrite next iter

    if (tid < 128) {
      const float recY = sAY + psum[1][tid];
      hY = D2C * hY + recY;
      pscY = D2C * pscY + hY;
    }
  }

  if (tid < 128) {
    rate[(size_t)bX * NH + sl * 128 + tid] = (float)scX / 1000.0f;
    rate[(size_t)bY * NH + sl * 128 + tid] = (float)scY / 1000.0f;
  }
}

// ---------------- kernel 4: out = rate @ W_out^T (unchanged) ----------------
__global__ __launch_bounds__(256) void out_gemv(const float* __restrict__ rate,
                                                const float* __restrict__ Wout,
                                                float* __restrict__ out) {
  __shared__ float rs[NH];
  const int b = blockIdx.x, tid = threadIdx.x;
  for (int i = tid; i < NH; i += 256) rs[i] = rate[(size_t)b * NH + i];
  __syncthreads();
  const float* wr = Wout + (size_t)tid * NH;
  float s = 0.0f;
  for (int hh = 0; hh < NH; hh += 4) {
    float4 w4 = *(const float4*)&wr[hh];
    s += rs[hh] * w4.x + rs[hh + 1] * w4.y + rs[hh + 2] * w4.z + rs[hh + 3] * w4.w;
  }
  out[(size_t)b * NO + tid] = s;
}

// ---------------- launch ----------------
extern "C" void kernel_launch(void* const* d_in, const int* in_sizes, int n_in,
                              void* d_out, int out_size, void* d_ws, size_t ws_size,
                              hipStream_t stream) {
  const float* x    = (const float*)d_in[0];
  const float* Win  = (const float*)d_in[1];
  const float* Wrec = (const float*)d_in[2];
  const float* Wout = (const float*)d_in[3];
  float* out = (float*)d_out;

  char* ws = (char*)d_ws;
  float* Iext = (float*)(ws + OFF_IEXT);
  float* WTS  = (float*)(ws + OFF_WTS);
  float* rate = (float*)(ws + OFF_RATE);
  u64*   sync = (u64*)(ws + OFF_SYNC);
  // Sync area: no memset needed -- 0xAA poison tag (0xAAAAAAAA) never equals
  // t+1 <= 1000; every block publishes X and Y before any wait can block;
  // deterministic reruns make prior-run tag matches benign (same payload).
  // Slot-overwrite safety: a block reaches publishX(t+2) only after pollY(t+1),
  // which needed every group member's publishY(t+1), which follows their
  // pollX(t+1)... unwinding to: all pollX(t) reads completed first.

  // Zero WTS so pad rows [NH,NHP) of each slice are 0.0f (the DUMMY target);
  // prep_wts then fills rows [0,NH).  Same-stream ordering serializes these.
  hipMemsetAsync(ws + OFF_WTS, 0, SZ_WTS, stream);

  prep_wts<<<dim3(16, 16), dim3(256), 0, stream>>>(Wrec, WTS);
  gemm_in<<<dim3((T_STEPS * B_SZ) / GBM, NH / GBN), dim3(256), 0, stream>>>(x, Win, Iext);
  scan_rsnn<<<dim3(NBLK), dim3(256), 0, stream>>>(Iext, WTS, rate, sync);
  out_gemv<<<dim3(B_SZ), dim3(256), 0, stream>>>(rate, Wout, out);
}

// Round 9
// 3333.630 us; speedup vs baseline: 1.6290x; 1.6290x over previous
//
#include <hip/hip_runtime.h>
#include <stdint.h>

// ---------------- problem constants ----------------
#define T_STEPS 1000
#define B_SZ    32
#define NI      512
#define NH      1024
#define NO      256

#define NSLICE  8     // neuron slices per batch; block (b,s) owns 128 neurons of batch b
#define NBLK    (B_SZ * NSLICE)   // 256 scan blocks, 1 per CU (proven residency regime)

// WTS slices get 16 pad rows; row NH (=1024) of each slice is ZERO and is
// the dummy gather target used to pad spike lists to multiples of 16.
#define NHP     (NH + 16)         // padded rows per slice
#define DUMMY   NH                // index of the zero row
#define BOFF    544               // slist offset of the B-half region (A max 512+pad<=544)

typedef unsigned long long u64;

// ---------------- ws layout (bytes) ----------------
#define OFF_IEXT 0ull
#define SZ_IEXT  ((unsigned long long)T_STEPS * B_SZ * NH * 4ull)   // 131,072,000
#define OFF_WTS  (OFF_IEXT + SZ_IEXT)
#define SZ_WTS   ((unsigned long long)NSLICE * NHP * 128 * 4ull)    // 4.06 MiB, WTS[s][i][jj], i<NHP
#define OFF_RATE (OFF_WTS + SZ_WTS)
#define SZ_RATE  ((unsigned long long)B_SZ * NH * 4ull)             // 128 KiB
#define OFF_SYNC (OFF_RATE + SZ_RATE)
#define SZ_SYNC  ((unsigned long long)2 * B_SZ * NSLICE * 4 * 8ull) // 16 KiB

// ---------------- agent-scope helpers ----------------
__device__ __forceinline__ u64 ld64_agent(const u64* p) {
  return __hip_atomic_load(p, __ATOMIC_RELAXED, __HIP_MEMORY_SCOPE_AGENT);
}
__device__ __forceinline__ void st64_agent(u64* p, u64 v) {
  __hip_atomic_store(p, v, __ATOMIC_RELAXED, __HIP_MEMORY_SCOPE_AGENT);
}

// ---------------- kernel 1: transpose W_rec -> WTS ----------------
// WTS[(s*NHP + i)*128 + jj] = W_rec[(128s+jj)*1024 + i]  (R5-verified mapping;
// pad rows [NH,NHP) stay zero from the memset)
__global__ __launch_bounds__(256) void prep_wts(const float* __restrict__ Wrec,
                                                float* __restrict__ WTS) {
  __shared__ float tile[64][65];
  const int tid = threadIdx.x;
  const int j0 = blockIdx.x * 64;
  const int i0 = blockIdx.y * 64;
  const int sl = j0 >> 7;
  const int jjb = j0 & 127;
#pragma unroll
  for (int k = 0; k < 16; ++k) {
    const int idx = k * 256 + tid;
    const int jl = idx >> 6, il = idx & 63;
    tile[jl][il] = Wrec[(size_t)(j0 + jl) * NH + i0 + il];
  }
  __syncthreads();
#pragma unroll
  for (int k = 0; k < 16; ++k) {
    const int idx = k * 256 + tid;
    const int il = idx >> 6, jl = idx & 63;
    WTS[((size_t)(sl * NHP + i0 + il)) * 128 + jjb + jl] = tile[jl][il];
  }
}

// ---------------- kernel 2: I_ext = x @ W_in^T  (fp32 tiled, unchanged) ----------------
// Kept fp32: bf16 I_ext would flip threshold crossings and cascade.
#define GBM 128
#define GBN 128
#define GBK 16
__global__ __launch_bounds__(256) void gemm_in(const float* __restrict__ X,
                                               const float* __restrict__ Win,
                                               float* __restrict__ I) {
  __shared__ float As[GBK][GBM + 4];
  __shared__ float Bs[GBK][GBN + 4];
  const int tid = threadIdx.x;
  const int m0 = blockIdx.x * GBM;
  const int n0 = blockIdx.y * GBN;
  const int tm = tid >> 4, tn = tid & 15;
  const int lr = tid >> 1, lk = (tid & 1) * 8;
  float acc[8][8] = {};
  for (int k0 = 0; k0 < NI; k0 += GBK) {
    float4 a0 = *(const float4*)&X[(size_t)(m0 + lr) * NI + k0 + lk];
    float4 a1 = *(const float4*)&X[(size_t)(m0 + lr) * NI + k0 + lk + 4];
    float4 b0 = *(const float4*)&Win[(size_t)(n0 + lr) * NI + k0 + lk];
    float4 b1 = *(const float4*)&Win[(size_t)(n0 + lr) * NI + k0 + lk + 4];
    As[lk + 0][lr] = a0.x; As[lk + 1][lr] = a0.y; As[lk + 2][lr] = a0.z; As[lk + 3][lr] = a0.w;
    As[lk + 4][lr] = a1.x; As[lk + 5][lr] = a1.y; As[lk + 6][lr] = a1.z; As[lk + 7][lr] = a1.w;
    Bs[lk + 0][lr] = b0.x; Bs[lk + 1][lr] = b0.y; Bs[lk + 2][lr] = b0.z; Bs[lk + 3][lr] = b0.w;
    Bs[lk + 4][lr] = b1.x; Bs[lk + 5][lr] = b1.y; Bs[lk + 6][lr] = b1.z; Bs[lk + 7][lr] = b1.w;
    __syncthreads();
#pragma unroll
    for (int k = 0; k < GBK; ++k) {
      float av[8], bv[8];
      *(float4*)&av[0] = *(const float4*)&As[k][tm * 8];
      *(float4*)&av[4] = *(const float4*)&As[k][tm * 8 + 4];
      *(float4*)&bv[0] = *(const float4*)&Bs[k][tn * 8];
      *(float4*)&bv[4] = *(const float4*)&Bs[k][tn * 8 + 4];
#pragma unroll
      for (int i2 = 0; i2 < 8; ++i2)
#pragma unroll
        for (int j2 = 0; j2 < 8; ++j2) acc[i2][j2] += av[i2] * bv[j2];
    }
    __syncthreads();
  }
#pragma unroll
  for (int i2 = 0; i2 < 8; ++i2) {
    float4 c0 = {acc[i2][0], acc[i2][1], acc[i2][2], acc[i2][3]};
    float4 c1 = {acc[i2][4], acc[i2][5], acc[i2][6], acc[i2][7]};
    *(float4*)&I[(size_t)(m0 + tm * 8 + i2) * NH + n0 + tn * 8] = c0;
    *(float4*)&I[(size_t)(m0 + tm * 8 + i2) * NH + n0 + tn * 8 + 4] = c1;
  }
}

// ---------------- kernel 3: persistent 1000-step scan, batch-diagonal ----------------
// R9 structure (proven 3.21 us/step, absmax 4.88e-4) with ONE change, cleanly
// attributed from R13: split poll/compact -- wave 2 handles words 0-15 (A),
// wave 3 words 16-31 (B), in parallel.  The compact offsets reproduce R9's
// exactly (B entries at B-exclusive-scan + BOFF), so list contents and order
// are bit-identical; R13 ran this code with unchanged absmax.  R13's 2-deep
// same-address poll is REMOVED (it added +20 MB of spin traffic and detection
// is round-trip-bound regardless of pipeline depth -- R13 post-mortem).
// State update, publish, padded 16-deep double-buffered gather, A+B
// association: verbatim R9.  FP trajectory unchanged.
__global__ __launch_bounds__(256) void scan_rsnn(const float* __restrict__ Iext,
                                                 const float* __restrict__ WTS,
                                                 float* __restrict__ rate,
                                                 u64* sync) {
  __shared__ unsigned short slist[1088];  // A: [0,544), B: [544,1088), padded
  __shared__ int scnt[2];                 // padded counts: [0]=A, [1]=B
  __shared__ float psumB[128];

  const int bid = blockIdx.x;
  const int b   = bid >> 3;
  const int sl  = bid & 7;
  const int tid = threadIdx.x;
  const int wv  = tid >> 6;
  const int ln  = tid & 63;
  const int jloc = tid & 127;               // gather target j within slice

  const float* wts = WTS + (size_t)sl * NHP * 128;

  const float D1 = 0.90483741803595957f;    // exp(-0.1)
  const float D2 = 0.81873075307798186f;    // exp(-0.2) == decay_syn

  // state (waves 0-1 only): neuron j = 128*sl + tid, tid<128
  float v = -60.0f, A1 = 0.0f, A2 = 0.0f, rf = 0.0f, h = 0.0f, psc = 0.0f;
  float ip = 0.0f;
  int sc = 0;

  if (tid < 128) ip = Iext[(size_t)b * NH + sl * 128 + tid];

  for (int t = 0; t < T_STEPS; ++t) {
    const int par = t & 1;
    u64* gbase = sync + ((size_t)(par * B_SZ + b)) * (NSLICE * 4);

    if (wv < 2) {
      // ---- state update (op order matches reference exactly) ----
      const float I = ip + psc;
      A1 *= D1; A2 *= D2;
      v = v + ((-60.0f - v) / 20.0f + (I + A1 + A2) / 2.0f);
      const bool inref = rf > 0.0f;
      if (inref) v = -60.0f;
      const bool spike = (!inref) && (v >= -45.0f);
      if (spike) { v = -60.0f; A1 += 1.0f; A2 += -2.0f; rf = 2.0f; sc++; }
      else       { rf = fmaxf(rf - 1.0f, 0.0f); }

      // ballot bit ln = spike(j = 128*sl + 64*wv + ln)
      const u64 bal = __ballot(spike);
      if (ln < 2) {
        const int w = wv * 2 + ln;          // word w covers neurons 128*sl+32w..
        const unsigned payload = ln ? (unsigned)(bal >> 32) : (unsigned)bal;
        st64_agent(&gbase[sl * 4 + w], (u64)payload | ((u64)(unsigned)(t + 1) << 32));
      }
      __builtin_amdgcn_sched_barrier(0);    // keep prefetch below the publish
      // prefetch next step's external current (512B contiguous per block)
      const int tn2 = (t + 1 < T_STEPS) ? t + 1 : t;
      ip = Iext[((size_t)tn2 * B_SZ + b) * NH + sl * 128 + tid];
    } else {
      // ---- split poll: wave 2 -> words 0-15 (A), wave 3 -> words 16-31 (B) ----
      // Single-outstanding-load spin (R9 mechanics); each half detects and
      // compacts independently, halving the serial compact time.
      const int half = wv - 2;              // 0 = A, 1 = B
      const u64* gp = &gbase[half * 16 + (ln & 15)];
      const unsigned want = (unsigned)(t + 1);
      u64 val = 0;
      for (;;) {
        if (ln < 16) val = ld64_agent(gp);
        const bool ok = (ln >= 16) || ((unsigned)(val >> 32) == want);
        if (__all(ok)) break;
      }
      // ---- compact my half's bitmap -> index list, (word, bit) ascending ----
      unsigned myw = (ln < 16) ? (unsigned)val : 0u;
      int inc = __popc(myw);
#pragma unroll
      for (int d = 1; d < 16; d <<= 1) {
        int y = __shfl_up(inc, d);
        if (ln >= d) inc += y;              // lanes 16+ contaminated, unused
      }
      const int cnt = __shfl(inc, 15);      // spikes in this half
      if (ln < 16) {
        int off = (inc - __popc(myw)) + half * BOFF;   // B region starts at BOFF
        const int base = (half * 16 + ln) * 32;        // word covers i = base..base+31
        unsigned m = myw;
        while (m) {
          const int bit = __builtin_ctz(m);
          m &= m - 1;
          slist[off++] = (unsigned short)(base + bit);
        }
      }
      // ---- pad to multiple of 16 plus one extra dummy batch (R9-proven) ----
      // DUMMY points at the slice's zero row: each pad add is s += +0.0f,
      // a bit-exact identity (exact cancellations round to +0, never -0).
      const int c16 = ((cnt + 15) & ~15) + 16;   // <= 544
      if (ln < c16 - cnt) slist[half * BOFF + cnt + ln] = (unsigned short)DUMMY;
      if (ln == 0) scnt[half] = c16;
    }
    __syncthreads();   // B1: slist/scnt ready

    // ---- tail-free double-buffered gather; adds applied in list order ----
    // A-half (tid<128): region [0,scnt[0]); B-half: [BOFF, BOFF+scnt[1]).
    float s = 0.0f;
    {
      const int kb   = (tid < 128) ? 0 : BOFF;
      const int kEnd = (tid < 128) ? scnt[0] : scnt[1];   // multiple of 16, >=16
      float wv16[16];
#pragma unroll
      for (int m2 = 0; m2 < 16; ++m2)
        wv16[m2] = wts[(size_t)slist[kb + m2] * 128 + jloc];
      for (int k = 16; k < kEnd; k += 16) {
        float nv16[16];
#pragma unroll
        for (int m2 = 0; m2 < 16; ++m2)         // issue batch k before folding k-16
          nv16[m2] = wts[(size_t)slist[kb + k + m2] * 128 + jloc];
#pragma unroll
        for (int m2 = 0; m2 < 16; ++m2) s += wv16[m2];   // in-order adds
#pragma unroll
        for (int m2 = 0; m2 < 16; ++m2) wv16[m2] = nv16[m2];
      }
#pragma unroll
      for (int m2 = 0; m2 < 16; ++m2) s += wv16[m2];     // last batch
    }
    if (tid >= 128) psumB[jloc] = s;
    __syncthreads();   // B2: B-half sums ready; also guards slist overwrite

    if (tid < 128) {
      const float rec = s + psumB[tid];     // same A+B association as R2-R9
      h = D2 * h + rec;
      psc = D2 * psc + h;                   // psc uses updated h (matches reference)
    }
  }

  if (tid < 128) rate[(size_t)b * NH + sl * 128 + tid] = (float)sc / 1000.0f;
}

// ---------------- kernel 4: out = rate @ W_out^T ----------------
__global__ __launch_bounds__(256) void out_gemv(const float* __restrict__ rate,
                                                const float* __restrict__ Wout,
                                                float* __restrict__ out) {
  __shared__ float rs[NH];
  const int b = blockIdx.x, tid = threadIdx.x;
  for (int i = tid; i < NH; i += 256) rs[i] = rate[(size_t)b * NH + i];
  __syncthreads();
  const float* wr = Wout + (size_t)tid * NH;
  float s = 0.0f;
  for (int hh = 0; hh < NH; hh += 4) {
    float4 w4 = *(const float4*)&wr[hh];
    s += rs[hh] * w4.x + rs[hh + 1] * w4.y + rs[hh + 2] * w4.z + rs[hh + 3] * w4.w;
  }
  out[(size_t)b * NO + tid] = s;
}

// ---------------- launch ----------------
extern "C" void kernel_launch(void* const* d_in, const int* in_sizes, int n_in,
                              void* d_out, int out_size, void* d_ws, size_t ws_size,
                              hipStream_t stream) {
  const float* x    = (const float*)d_in[0];
  const float* Win  = (const float*)d_in[1];
  const float* Wrec = (const float*)d_in[2];
  const float* Wout = (const float*)d_in[3];
  float* out = (float*)d_out;

  char* ws = (char*)d_ws;
  float* Iext = (float*)(ws + OFF_IEXT);
  float* WTS  = (float*)(ws + OFF_WTS);
  float* rate = (float*)(ws + OFF_RATE);
  u64*   sync = (u64*)(ws + OFF_SYNC);
  // Sync area: no memset needed -- 0xAA poison tag (0xAAAAAAAA) never equals
  // t+1 <= 1000, and every block publishes before its poll waves can block;
  // deterministic reruns make prior-run tag matches benign (same payload).

  // Zero WTS so pad rows [NH,NHP) of each slice are 0.0f (the DUMMY target);
  // prep_wts then fills rows [0,NH).  Same-stream ordering serializes these.
  hipMemsetAsync(ws + OFF_WTS, 0, SZ_WTS, stream);

  prep_wts<<<dim3(16, 16), dim3(256), 0, stream>>>(Wrec, WTS);
  gemm_in<<<dim3((T_STEPS * B_SZ) / GBM, NH / GBN), dim3(256), 0, stream>>>(x, Win, Iext);
  scan_rsnn<<<dim3(NBLK), dim3(256), 0, stream>>>(Iext, WTS, rate, sync);
  out_gemv<<<dim3(B_SZ), dim3(256), 0, stream>>>(rate, Wout, out);
}